// Round 1
// baseline (652.304 us; speedup 1.0000x reference)
//
#include <hip/hip_runtime.h>
#include <cstdint>

typedef unsigned short u16;
typedef unsigned int u32;
typedef float floatx4 __attribute__((ext_vector_type(4)));
typedef __bf16 bf16x8 __attribute__((ext_vector_type(8)));
typedef u16 u16x4 __attribute__((ext_vector_type(4)));

__device__ __forceinline__ u16 f2b(float f) {
  u32 u = __builtin_bit_cast(u32, f);
  u32 r = (u + 0x7fffu + ((u >> 16) & 1u)) >> 16;
  return (u16)r;
}
__device__ __forceinline__ float b2f(u16 b) {
  return __builtin_bit_cast(float, (u32)b << 16);
}
__device__ __forceinline__ float sigf(float x) { return 1.f / (1.f + __expf(-x)); }
__device__ __forceinline__ float tanhfast(float x) { return 2.f / (1.f + __expf(-2.f * x)) - 1.f; }

#define GLDS(gp, lp) __builtin_amdgcn_global_load_lds( \
    (const __attribute__((address_space(1))) u32*)(gp), \
    (__attribute__((address_space(3))) u32*)(lp), 16, 0, 0)

// C = A @ W^T.  A: [M,K] bf16 K-contig, W: [N,K] bf16 K-contig.
// STATS: atomically accumulate per-column sum/sumsq of C (fp32).
// BIAS:  C is fp32 with bias add; else C is bf16.
template <int STATS, int BIAS>
__global__ __launch_bounds__(256) void gemm_bt(
    const u16* __restrict__ A, const u16* __restrict__ W, void* __restrict__ Cv,
    int N, int K, float* __restrict__ ssum, float* __restrict__ ssq,
    const float* __restrict__ bias) {
  __shared__ u16 As[128 * 32];
  __shared__ u16 Bs[128 * 32];
  const int tid = threadIdx.x;
  const int lane = tid & 63;
  const int wave = tid >> 6;
  const int wm = (wave >> 1) << 6;
  const int wn = (wave & 1) << 6;
  const int m0 = blockIdx.y * 128;
  const int n0 = blockIdx.x * 128;
  const u16* Ab = A + (size_t)m0 * K;
  const u16* Wb = W + (size_t)n0 * K;
  const size_t soff = (size_t)(tid >> 2) * K + ((tid & 3) << 3);
  const size_t soff2 = soff + (size_t)64 * K;
  const int fr = lane & 15;  // n for B/C, m for A
  const int fq = lane >> 4;  // quad
  const int aoff = fr * 32 + fq * 8;

  floatx4 acc[4][4] = {};

  for (int k0 = 0; k0 < K; k0 += 32) {
    __syncthreads();
    GLDS(Ab + soff + k0, &As[tid * 8]);
    GLDS(Ab + soff2 + k0, &As[tid * 8 + 2048]);
    GLDS(Wb + soff + k0, &Bs[tid * 8]);
    GLDS(Wb + soff2 + k0, &Bs[tid * 8 + 2048]);
    __syncthreads();
    bf16x8 af[4], bfv[4];
#pragma unroll
    for (int i = 0; i < 4; ++i) af[i] = *(const bf16x8*)&As[(wm + i * 16) * 32 + aoff];
#pragma unroll
    for (int j = 0; j < 4; ++j) bfv[j] = *(const bf16x8*)&Bs[(wn + j * 16) * 32 + aoff];
#pragma unroll
    for (int i = 0; i < 4; ++i)
#pragma unroll
      for (int j = 0; j < 4; ++j)
        acc[i][j] = __builtin_amdgcn_mfma_f32_16x16x32_bf16(af[i], bfv[j], acc[i][j], 0, 0, 0);
  }

  if (BIAS) {
    float* C = (float*)Cv;
#pragma unroll
    for (int i = 0; i < 4; ++i)
#pragma unroll
      for (int j = 0; j < 4; ++j) {
        const int col = n0 + wn + j * 16 + fr;
        const float bv = bias[col];
#pragma unroll
        for (int r = 0; r < 4; ++r) {
          const int row = m0 + wm + i * 16 + fq * 4 + r;
          C[(size_t)row * N + col] = acc[i][j][r] + bv;
        }
      }
  } else {
    u16* C = (u16*)Cv;
#pragma unroll
    for (int i = 0; i < 4; ++i)
#pragma unroll
      for (int j = 0; j < 4; ++j) {
        const int col = n0 + wn + j * 16 + fr;
#pragma unroll
        for (int r = 0; r < 4; ++r) {
          const int row = m0 + wm + i * 16 + fq * 4 + r;
          C[(size_t)row * N + col] = f2b(acc[i][j][r]);
        }
      }
  }

  if (STATS) {
#pragma unroll
    for (int j = 0; j < 4; ++j) {
      float s = 0.f, q = 0.f;
#pragma unroll
      for (int i = 0; i < 4; ++i)
#pragma unroll
        for (int r = 0; r < 4; ++r) {
          const float v = acc[i][j][r];
          s += v;
          q += v * v;
        }
      s += __shfl_xor(s, 16);
      s += __shfl_xor(s, 32);
      q += __shfl_xor(q, 16);
      q += __shfl_xor(q, 32);
      if (fq == 0) {
        atomicAdd(&ssum[n0 + wn + j * 16 + fr], s);
        atomicAdd(&ssq[n0 + wn + j * 16 + fr], q);
      }
    }
  }
}

// concat [x | y | zeros] -> bf16 [B, 288]
__global__ void pad_inp_k(const float* __restrict__ x, const float* __restrict__ y,
                          u16* __restrict__ o) {
  const int idx = blockIdx.x * 256 + threadIdx.x;  // B*288
  const int b = idx / 288;
  const int c = idx - b * 288;
  float v = 0.f;
  if (c < 256) v = x[b * 256 + c];
  else if (c == 256) v = y[b];
  o[idx] = f2b(v);
}

// Wx0 [2048,257] -> bf16 [2048,288] zero-padded
__global__ void pad_w_k(const float* __restrict__ w, u16* __restrict__ o) {
  const int idx = blockIdx.x * 256 + threadIdx.x;  // 2048*288
  const int r = idx / 288;
  const int c = idx - r * 288;
  o[idx] = f2b(c < 257 ? w[r * 257 + c] : 0.f);
}

__global__ void f2b_k(const float4* __restrict__ in, u16x4* __restrict__ o, int n4) {
  const int idx = blockIdx.x * 256 + threadIdx.x;
  if (idx < n4) {
    const float4 v = in[idx];
    u16x4 r;
    r.x = f2b(v.x);
    r.y = f2b(v.y);
    r.z = f2b(v.z);
    r.w = f2b(v.w);
    o[idx] = r;
  }
}

// stats layout per layer: [sum_x, sq_x, sum_h, sq_h] each 2048
// coef layout per layer:  [ax, ah, cb] each 2048
__global__ void coef_k(const float* __restrict__ st, const float* __restrict__ gx,
                       const float* __restrict__ bx, const float* __restrict__ gh,
                       const float* __restrict__ bh, float* __restrict__ cf, float invB) {
  const int j = blockIdx.x * 256 + threadIdx.x;  // 2048
  const float mx = st[j] * invB;
  const float vx = st[2048 + j] * invB - mx * mx;
  const float ax = gx[j] * rsqrtf(vx + 1e-5f);
  const float mh = st[4096 + j] * invB;
  const float vh = st[6144 + j] * invB - mh * mh;
  const float ah = gh[j] * rsqrtf(vh + 1e-5f);
  cf[j] = ax;
  cf[2048 + j] = ah;
  cf[4096 + j] = bx[j] - mx * ax + bh[j] - mh * ah;
}

// fused BN-affine + LSTM cell; 2 columns per thread
__global__ void cell_k(const u16* __restrict__ Zx, const u16* __restrict__ Zh,
                       const float* __restrict__ coef, const float* __restrict__ cin,
                       float* __restrict__ hout, float* __restrict__ cout,
                       u16* __restrict__ hb) {
  const int idx = blockIdx.x * 256 + threadIdx.x;  // B*256
  const int b = idx >> 8;
  const int j2 = (idx & 255) << 1;
  const size_t rb = (size_t)b << 11;
  float gv[4][2];
#pragma unroll
  for (int g = 0; g < 4; ++g) {
    const int col = (g << 9) + j2;
    const u32 zx = *(const u32*)(Zx + rb + col);
    const u32 zh = *(const u32*)(Zh + rb + col);
#pragma unroll
    for (int t = 0; t < 2; ++t) {
      const float zxv = b2f((u16)(zx >> (16 * t)));
      const float zhv = b2f((u16)(zh >> (16 * t)));
      gv[g][t] = coef[col + t] * zxv + coef[2048 + col + t] * zhv + coef[4096 + col + t];
    }
  }
  const size_t ob = ((size_t)b << 9) + j2;
  const float2 cp = *(const float2*)(cin + ob);
  float cn[2], hn[2];
#pragma unroll
  for (int t = 0; t < 2; ++t) {
    const float cprev = t ? cp.y : cp.x;
    const float cc = sigf(gv[0][t]) * cprev + sigf(gv[1][t]) * tanhfast(gv[3][t]);
    cn[t] = cc;
    hn[t] = sigf(gv[2][t]) * tanhfast(cc);
  }
  *(float2*)(cout + ob) = make_float2(cn[0], cn[1]);
  *(float2*)(hout + ob) = make_float2(hn[0], hn[1]);
  *(u32*)(hb + ob) = (u32)f2b(hn[0]) | ((u32)f2b(hn[1]) << 16);
}

extern "C" void kernel_launch(void* const* d_in, const int* in_sizes, int n_in,
                              void* d_out, int out_size, void* d_ws, size_t ws_size,
                              hipStream_t stream) {
  (void)in_sizes; (void)n_in; (void)out_size; (void)ws_size;
  constexpr int B = 16384, H = 512, G = 2048, KP = 288, K1 = 512, NOUT = 256;

  const float* x = (const float*)d_in[0];
  const float* y = (const float*)d_in[1];
  const float* h0 = (const float*)d_in[2];
  const float* c0 = (const float*)d_in[3];
  const float* Wx0 = (const float*)d_in[4];
  const float* Wh0 = (const float*)d_in[5];
  const float* gx0 = (const float*)d_in[6];
  const float* bx0 = (const float*)d_in[7];
  const float* gh0 = (const float*)d_in[8];
  const float* bh0 = (const float*)d_in[9];
  const float* Wx1 = (const float*)d_in[10];
  const float* Wh1 = (const float*)d_in[11];
  const float* gx1 = (const float*)d_in[12];
  const float* bx1 = (const float*)d_in[13];
  const float* gh1 = (const float*)d_in[14];
  const float* bh1 = (const float*)d_in[15];
  const float* Wo = (const float*)d_in[16];
  const float* bo = (const float*)d_in[17];

  char* p = (char*)d_ws;
  u16* Zx = (u16*)p;   p += (size_t)B * G * 2;
  u16* Zh = (u16*)p;   p += (size_t)B * G * 2;
  u16* h0b = (u16*)p;  p += (size_t)2 * B * H * 2;
  u16* h1b = (u16*)p;  p += (size_t)B * H * 2;   // reused for h2 bf16
  u16* inpb = (u16*)p; p += (size_t)B * KP * 2;
  u16* wx0b = (u16*)p; p += (size_t)G * KP * 2;
  u16* wh0b = (u16*)p; p += (size_t)G * K1 * 2;
  u16* wx1b = (u16*)p; p += (size_t)G * K1 * 2;
  u16* wh1b = (u16*)p; p += (size_t)G * K1 * 2;
  u16* wob = (u16*)p;  p += (size_t)NOUT * K1 * 2;
  float* stats = (float*)p; p += (size_t)8 * G * 4;
  float* coef = (float*)p;  p += (size_t)6 * G * 4;

  float* out_o = (float*)d_out;                     // [B,256]
  float* h_o = out_o + (size_t)B * NOUT;            // [2,B,512]
  float* c_o = h_o + (size_t)2 * B * H;             // [2,B,512]

  hipMemsetAsync(stats, 0, (size_t)8 * G * sizeof(float), stream);

  pad_inp_k<<<B * KP / 256, 256, 0, stream>>>(x, y, inpb);
  pad_w_k<<<G * KP / 256, 256, 0, stream>>>(Wx0, wx0b);
  f2b_k<<<2 * B * H / 4 / 256, 256, 0, stream>>>((const float4*)h0, (u16x4*)h0b, 2 * B * H / 4);
  f2b_k<<<G * K1 / 4 / 256, 256, 0, stream>>>((const float4*)Wh0, (u16x4*)wh0b, G * K1 / 4);
  f2b_k<<<G * K1 / 4 / 256, 256, 0, stream>>>((const float4*)Wx1, (u16x4*)wx1b, G * K1 / 4);
  f2b_k<<<G * K1 / 4 / 256, 256, 0, stream>>>((const float4*)Wh1, (u16x4*)wh1b, G * K1 / 4);
  f2b_k<<<NOUT * K1 / 4 / 256, 256, 0, stream>>>((const float4*)Wo, (u16x4*)wob, NOUT * K1 / 4);

  const dim3 blk(256);
  const dim3 gbig(G / 128, B / 128);

  // layer 0
  gemm_bt<1, 0><<<gbig, blk, 0, stream>>>(inpb, wx0b, Zx, G, KP, stats + 0 * G, stats + 1 * G, nullptr);
  gemm_bt<1, 0><<<gbig, blk, 0, stream>>>(h0b, wh0b, Zh, G, K1, stats + 2 * G, stats + 3 * G, nullptr);
  coef_k<<<G / 256, 256, 0, stream>>>(stats, gx0, bx0, gh0, bh0, coef, 1.f / B);
  cell_k<<<B, 256, 0, stream>>>(Zx, Zh, coef, c0, h_o, c_o, h1b);

  // layer 1
  gemm_bt<1, 0><<<gbig, blk, 0, stream>>>(h1b, wx1b, Zx, G, K1, stats + 4 * G, stats + 5 * G, nullptr);
  gemm_bt<1, 0><<<gbig, blk, 0, stream>>>(h0b + (size_t)B * H, wh1b, Zh, G, K1, stats + 6 * G, stats + 7 * G, nullptr);
  coef_k<<<G / 256, 256, 0, stream>>>(stats + 4 * G, gx1, bx1, gh1, bh1, coef + 3 * G, 1.f / B);
  cell_k<<<B, 256, 0, stream>>>(Zx, Zh, coef + 3 * G, c0 + (size_t)B * H,
                                h_o + (size_t)B * H, c_o + (size_t)B * H, h1b);

  // output projection
  const dim3 gout(NOUT / 128, B / 128);
  gemm_bt<0, 1><<<gout, blk, 0, stream>>>(h1b, wob, out_o, NOUT, K1, nullptr, nullptr, bo);
}